// Round 5
// baseline (414.499 us; speedup 1.0000x reference)
//
#include <hip/hip_runtime.h>
#include <hip/hip_fp16.h>

#define DIM 128

typedef _Float16 half8_t __attribute__((ext_vector_type(8)));
typedef float f32x4 __attribute__((ext_vector_type(4)));
typedef float f32x4v __attribute__((ext_vector_type(4)));

#define EB1 2048   // edge blocks in k1
#define EB3 2048   // edge blocks in k3b

// ws: hn f16[n*128] (25.6MB) | Wf f16[16384] | row_start i32[n+1 pad] |
//     cur i32[n pad] | bsum i32[64] | ebuf i32[ne]

// Blocks [0,EB1): deg count via global no-return atomics (row_start pre-zeroed).
// Blocks [EB1,EB1+8): build Wf table:
// Wf[((tile*4+kk)*64+lane)*8+j] = W[tile*16+(lane&15)][kk*32+(lane>>4)*8+j]
__global__ __launch_bounds__(256) void k1_deg(const int* __restrict__ dst,
                                              int* __restrict__ rs,
                                              int ne,
                                              const float* __restrict__ W,
                                              _Float16* __restrict__ Wf) {
    int blk = blockIdx.x;
    int t = threadIdx.x;
    if (blk >= EB1) {
        int idx = (blk - EB1) * 256 + t;  // 0..2047
        int tile = idx >> 8;
        int kk = (idx >> 6) & 3;
        int lane = idx & 63;
        int nn = lane & 15, quad = lane >> 4;
        const float* wr = W + (tile * 16 + nn) * DIM + kk * 32 + quad * 8;
        _Float16* o = Wf + (size_t)idx * 8;
#pragma unroll
        for (int j = 0; j < 8; ++j) o[j] = (_Float16)wr[j];
        return;
    }
    int stride = EB1 * 256;
    for (int i = blk * 256 + t; i < ne; i += stride)
        atomicAdd(&rs[dst[i]], 1);
}

// Exclusive scan in 2048-chunks (512 thr, 4 elem/thread, shfl wave-scan);
// bsum[chunk] = raw chunk total.
__global__ __launch_bounds__(512) void k2_scan(int* __restrict__ g,
                                               int* __restrict__ bsum, int M) {
    __shared__ int wsum[8];
    int t = threadIdx.x;
    int base = blockIdx.x * 2048 + t * 4;
    int4 v;
    if (base + 3 < M) v = *(const int4*)(g + base);
    else {
        v.x = (base + 0 < M) ? g[base + 0] : 0;
        v.y = (base + 1 < M) ? g[base + 1] : 0;
        v.z = (base + 2 < M) ? g[base + 2] : 0;
        v.w = (base + 3 < M) ? g[base + 3] : 0;
    }
    int s3 = v.x + v.y + v.z + v.w;
    int lane = t & 63, wv = t >> 6;
    int x = s3;
#pragma unroll
    for (int off = 1; off < 64; off <<= 1) {
        int y = __shfl_up(x, off, 64);
        if (lane >= off) x += y;
    }
    if (lane == 63) wsum[wv] = x;
    __syncthreads();
    int woff = 0;
    for (int i = 0; i < wv; ++i) woff += wsum[i];
    int ex = woff + x - s3;
    int4 o;
    o.x = ex; o.y = ex + v.x; o.z = o.y + v.y; o.w = o.z + v.z;
    if (base + 3 < M) *(int4*)(g + base) = o;
    else {
        if (base + 0 < M) g[base + 0] = o.x;
        if (base + 1 < M) g[base + 1] = o.y;
        if (base + 2 < M) g[base + 2] = o.z;
        if (base + 3 < M) g[base + 3] = o.w;
    }
    if (t == 0) {
        int s = 0;
#pragma unroll
        for (int i = 0; i < 8; ++i) s += wsum[i];
        bsum[blockIdx.x] = s;
    }
}

// Fold chunk offsets (wave-0 shfl scan of bsum, nsc<=64) -> final row_start;
// init cur[] = row_start.
__global__ __launch_bounds__(256) void k3a_fix(int* __restrict__ rs,
                                               int* __restrict__ cur,
                                               const int* __restrict__ bsum,
                                               int n, int nsc) {
    __shared__ int gbl[64];
    int t = threadIdx.x;
    if (t < 64) {
        int v = (t < nsc) ? bsum[t] : 0;
        int x = v;
#pragma unroll
        for (int off = 1; off < 64; off <<= 1) {
            int y = __shfl_up(x, off, 64);
            if ((t & 63) >= off) x += y;
        }
        gbl[t] = x - v;   // exclusive
    }
    __syncthreads();
    int i = blockIdx.x * 256 + t;
    if (i <= n) {
        int a = rs[i] + gbl[i >> 11];
        rs[i] = a;
        if (i < n) cur[i] = a;
    }
}

// Blocks [0,EB3): edge scatter: pos = atomicAdd(cur[dst]); ebuf[pos] = src.
// Blocks [EB3,..): hn pack: hn[i] = f16(h[i] * rsqrt(max(deg,1))).
__global__ __launch_bounds__(256) void k3b_scat(const int* __restrict__ src,
                                                const int* __restrict__ dst,
                                                int* __restrict__ cur,
                                                int* __restrict__ ebuf,
                                                const int* __restrict__ rs,
                                                const float* __restrict__ h,
                                                float2* __restrict__ hn,
                                                int ne, int n32) {
    int blk = blockIdx.x;
    int t = threadIdx.x;
    if (blk < EB3) {
        int stride = EB3 * 256;
        for (int i = blk * 256 + t; i < ne; i += stride) {
            int s = src[i];
            int d = dst[i];
            int pos = atomicAdd(&cur[d], 1);
            __builtin_nontemporal_store(s, &ebuf[pos]);
        }
        return;
    }
    int i = (blk - EB3) * 256 + t;
    if (i < n32) {
        int node = i >> 5;
        int dg = rs[node + 1] - rs[node];
        float sc = rsqrtf((float)(dg > 1 ? dg : 1));
        f32x4v v = __builtin_nontemporal_load((const f32x4v*)h + i);
        union { __half2 h2[2]; float2 f2; } u;
        u.h2[0] = __floats2half2_rn(v.x * sc, v.y * sc);
        u.h2[1] = __floats2half2_rn(v.z * sc, v.w * sc);
        hn[i] = u.f2;
    }
}

// Phase 1: 16 groups x 32 lanes; group g aggregates 4 nodes {blk*64+it*16+g}
// (degree averaging over 4 draws -> balanced barrier), x8-unrolled loads.
// Fabric-bound at ~3.2TB/s random lines (round-1 A/B) -> proven structure kept.
// Phase 2: 8 waves; wave w = col-tile; 4 row-tiles x 4 chained
// mfma_f32_16x16x32_f16 (K=128), bf reused across row-tiles. NT out stores.
__global__ __launch_bounds__(512) void gather_gemm(const float2* __restrict__ hn,
                                                   const int* __restrict__ ebuf,
                                                   const int* __restrict__ rs,
                                                   const _Float16* __restrict__ Wf,
                                                   const float* __restrict__ b,
                                                   float* __restrict__ out, int n) {
    __shared__ _Float16 xs[64 * 136];
    int tid = threadIdx.x;
    int g = tid >> 5, lane = tid & 31;

#pragma unroll
    for (int it = 0; it < 4; ++it) {
        int row = it * 16 + g;
        int node = blockIdx.x * 64 + row;
        union { __half2 h2[2]; float2 f2; } u;
        if (node < n) {
            int s0 = rs[node];
            int s1 = rs[node + 1];
            __half2 a0 = __floats2half2_rn(0.f, 0.f), a1 = a0;
            int i = s0;
            for (; i + 7 < s1; i += 8) {
                int e0 = ebuf[i], e1 = ebuf[i + 1], e2 = ebuf[i + 2], e3 = ebuf[i + 3];
                int e4 = ebuf[i + 4], e5 = ebuf[i + 5], e6 = ebuf[i + 6], e7 = ebuf[i + 7];
                float2 r0 = hn[(size_t)e0 * 32 + lane];
                float2 r1 = hn[(size_t)e1 * 32 + lane];
                float2 r2 = hn[(size_t)e2 * 32 + lane];
                float2 r3 = hn[(size_t)e3 * 32 + lane];
                float2 r4 = hn[(size_t)e4 * 32 + lane];
                float2 r5 = hn[(size_t)e5 * 32 + lane];
                float2 r6 = hn[(size_t)e6 * 32 + lane];
                float2 r7 = hn[(size_t)e7 * 32 + lane];
                const __half2* q0 = (const __half2*)&r0;
                const __half2* q1 = (const __half2*)&r1;
                const __half2* q2 = (const __half2*)&r2;
                const __half2* q3 = (const __half2*)&r3;
                const __half2* q4 = (const __half2*)&r4;
                const __half2* q5 = (const __half2*)&r5;
                const __half2* q6 = (const __half2*)&r6;
                const __half2* q7 = (const __half2*)&r7;
                a0 = __hadd2(a0, q0[0]); a1 = __hadd2(a1, q0[1]);
                a0 = __hadd2(a0, q1[0]); a1 = __hadd2(a1, q1[1]);
                a0 = __hadd2(a0, q2[0]); a1 = __hadd2(a1, q2[1]);
                a0 = __hadd2(a0, q3[0]); a1 = __hadd2(a1, q3[1]);
                a0 = __hadd2(a0, q4[0]); a1 = __hadd2(a1, q4[1]);
                a0 = __hadd2(a0, q5[0]); a1 = __hadd2(a1, q5[1]);
                a0 = __hadd2(a0, q6[0]); a1 = __hadd2(a1, q6[1]);
                a0 = __hadd2(a0, q7[0]); a1 = __hadd2(a1, q7[1]);
            }
            for (; i + 3 < s1; i += 4) {
                int e0 = ebuf[i], e1 = ebuf[i + 1], e2 = ebuf[i + 2], e3 = ebuf[i + 3];
                float2 r0 = hn[(size_t)e0 * 32 + lane];
                float2 r1 = hn[(size_t)e1 * 32 + lane];
                float2 r2 = hn[(size_t)e2 * 32 + lane];
                float2 r3 = hn[(size_t)e3 * 32 + lane];
                const __half2* q0 = (const __half2*)&r0;
                const __half2* q1 = (const __half2*)&r1;
                const __half2* q2 = (const __half2*)&r2;
                const __half2* q3 = (const __half2*)&r3;
                a0 = __hadd2(a0, q0[0]); a1 = __hadd2(a1, q0[1]);
                a0 = __hadd2(a0, q1[0]); a1 = __hadd2(a1, q1[1]);
                a0 = __hadd2(a0, q2[0]); a1 = __hadd2(a1, q2[1]);
                a0 = __hadd2(a0, q3[0]); a1 = __hadd2(a1, q3[1]);
            }
            for (; i < s1; ++i) {
                int e0 = ebuf[i];
                float2 r0 = hn[(size_t)e0 * 32 + lane];
                const __half2* q0 = (const __half2*)&r0;
                a0 = __hadd2(a0, q0[0]); a1 = __hadd2(a1, q0[1]);
            }
            int dn = s1 - s0;
            float nd = rsqrtf((float)(dn > 1 ? dn : 1));
            float2 f0 = __half22float2(a0), f1 = __half22float2(a1);
            u.h2[0] = __floats2half2_rn(f0.x * nd, f0.y * nd);
            u.h2[1] = __floats2half2_rn(f1.x * nd, f1.y * nd);
        } else {
            u.h2[0] = __floats2half2_rn(0.f, 0.f);
            u.h2[1] = u.h2[0];
        }
        *(float2*)(xs + row * 136 + lane * 4) = u.f2;
    }
    __syncthreads();

    int w = tid >> 6;     // wave = col-tile
    int wl = tid & 63;
    int cn = wl & 15;
    int quad = wl >> 4;

    f32x4 acc[4] = {{0.f, 0.f, 0.f, 0.f}, {0.f, 0.f, 0.f, 0.f},
                    {0.f, 0.f, 0.f, 0.f}, {0.f, 0.f, 0.f, 0.f}};
#pragma unroll
    for (int kk = 0; kk < 4; ++kk) {
        half8_t bf = ((const half8_t*)Wf)[(w * 4 + kk) * 64 + wl];
#pragma unroll
        for (int rt = 0; rt < 4; ++rt) {
            half8_t af = *(const half8_t*)(xs + (rt * 16 + cn) * 136 + kk * 32 + quad * 8);
            acc[rt] = __builtin_amdgcn_mfma_f32_16x16x32_f16(af, bf, acc[rt], 0, 0, 0);
        }
    }
    float bj = b[w * 16 + cn];
    int node0 = blockIdx.x * 64;
#pragma unroll
    for (int rt = 0; rt < 4; ++rt) {
#pragma unroll
        for (int r = 0; r < 4; ++r) {
            int node = node0 + rt * 16 + quad * 4 + r;
            if (node < n)
                __builtin_nontemporal_store(acc[rt][r] + bj,
                                            &out[(size_t)node * DIM + w * 16 + cn]);
        }
    }
}

extern "C" void kernel_launch(void* const* d_in, const int* in_sizes, int n_in,
                              void* d_out, int out_size, void* d_ws, size_t ws_size,
                              hipStream_t stream) {
    const float* h = (const float*)d_in[0];
    const float* W = (const float*)d_in[1];
    const float* b = (const float*)d_in[2];
    const int* esrc = (const int*)d_in[3];
    const int* edst = (const int*)d_in[4];
    float* out = (float*)d_out;

    int n = in_sizes[0] / DIM;   // 100000
    int ne = in_sizes[3];        // 1600000
    int n32 = n * 32;

    float2* hn = (float2*)d_ws;                       // n*32 float2 (25.6MB)
    _Float16* Wf = (_Float16*)(hn + (size_t)n * 32);  // 16384 halfs
    int* row_start = (int*)(Wf + 16384);              // n+1 (padded)
    int* cur = row_start + ((n + 4) & ~3);            // n (padded)
    int* bsum = cur + ((n + 3) & ~3);                 // 64
    int* ebuf = bsum + 64;                            // ne

    int M = n + 1;
    int nsc = (M + 2047) / 2048;                      // 49 (<=64 required)

    hipMemsetAsync(row_start, 0, (size_t)(n + 1) * sizeof(int), stream);
    k1_deg<<<EB1 + 8, 256, 0, stream>>>(edst, row_start, ne, W, Wf);
    k2_scan<<<nsc, 512, 0, stream>>>(row_start, bsum, M);
    k3a_fix<<<(M + 255) / 256, 256, 0, stream>>>(row_start, cur, bsum, n, nsc);
    k3b_scat<<<EB3 + (n32 + 255) / 256, 256, 0, stream>>>(esrc, edst, cur, ebuf,
                                                          row_start, h, hn, ne, n32);
    gather_gemm<<<(n + 63) / 64, 512, 0, stream>>>(hn, ebuf, row_start, Wf, b, out, n);
}